// Round 3
// baseline (763.069 us; speedup 1.0000x reference)
//
#include <hip/hip_runtime.h>

#define BATCH 4
#define DIM   1536
#define SEQ   4096
#define NST   16
#define NCHAN (BATCH*DIM)
#define T     16       // timesteps per tile (64B per channel-row per access)
#define LBSTR 20       // LDS B/C tile stride ([t][n], padded)

#define LOG2E 1.4426950408889634f

// softplus matching jax.nn.softplus = log1p(exp(z)), overflow-safe
__device__ __forceinline__ float softplus_f(float z) {
    return (z > 20.f) ? z : __logf(1.f + __expf(z));
}
__device__ __forceinline__ float exp2_hw(float z) {
    return __builtin_amdgcn_exp2f(z);
}

// DPP quad_perm helper (compile-time control). All lanes active, uniform flow.
template<int CTRL>
__device__ __forceinline__ float dpp_qp(float v) {
    return __int_as_float(
        __builtin_amdgcn_mov_dpp(__float_as_int(v), CTRL, 0xf, 0xf, true));
}
// sum across the 4 lanes of a quad (result in all 4 lanes)
__device__ __forceinline__ float quad_sum(float v) {
    v += dpp_qp<0xB1>(v);   // quad_perm [1,0,3,2]
    v += dpp_qp<0x4E>(v);   // quad_perm [2,3,0,1]
    return v;
}

// ---------------------------------------------------------------------------
// Quad-per-channel decomposition (round-2), now with:
//  - 2-tile-deep u/delta prefetch (3-buffer rotation, fully unrolled)
//  - CLEN=64 primary (more blocks -> full 32-wave/CU occupancy, clean tail)
//  - launch_bounds(256,8), dtu-broadcast + D*u folded at writeout
// ---------------------------------------------------------------------------

// ---------------- Phase A: per-(channel,chunk) summaries ----------------
template<int CLEN>
__global__ __launch_bounds__(256, 8) void ssm_phaseA(
    const float* __restrict__ u, const float* __restrict__ delta,
    const float* __restrict__ Bm, const float* __restrict__ A,
    const float* __restrict__ dbias,
    float* __restrict__ sumdt_out, float* __restrict__ S_out)
{
    constexpr int NT = CLEN / T;
    __shared__ float lB[4 * T * LBSTR];

    const int tid = threadIdx.x;
    const int w   = tid >> 6;
    const int l   = tid & 63;
    const int q   = l >> 2;      // quad index = channel row in wave = B state row
    const int sub = l & 3;       // lane within quad: owns states cj..cj+3
    const int cj  = sub << 2;

    const int ch0 = blockIdx.x * 64;
    const int ch  = ch0 + w * 16 + q;
    const int d   = ch % DIM;
    const int bb  = ch0 / DIM;
    const int k   = blockIdx.y;
    const int s0  = k * CLEN;

    float* LB = &lB[w * T * LBSTR];

    float A2[4];
    {
        const float4 av = *(const float4*)(A + (size_t)d * NST + cj);
        A2[0] = av.x * LOG2E; A2[1] = av.y * LOG2E;
        A2[2] = av.z * LOG2E; A2[3] = av.w * LOG2E;
    }
    const float sbias = dbias[d];

    const size_t ubase = (size_t)ch * SEQ + s0;
    const size_t bbase = ((size_t)bb * NST + q) * SEQ + s0;

    // 3-buffer rotation: tiles t, t+1 preloaded; loop loads t+2
    float4 PU[3], PD[3], RB;
    PU[0] = *(const float4*)(u + ubase + cj);
    PD[0] = *(const float4*)(delta + ubase + cj);
    PU[1] = *(const float4*)(u + ubase + T + cj);
    PD[1] = *(const float4*)(delta + ubase + T + cj);
    RB = *(const float4*)(Bm + bbase + cj);

    float S[4] = {0.f, 0.f, 0.f, 0.f};
    float sumdt = 0.f;

#pragma unroll
    for (int t = 0; t < NT; ++t) {
        const int cb = t % 3;        // constant after unroll
        const int ss = t * T;

        // stage B tile t (writes issue early; complete while we wait on vmcnt)
        LB[(cj + 0) * LBSTR + q] = RB.x;
        LB[(cj + 1) * LBSTR + q] = RB.y;
        LB[(cj + 2) * LBSTR + q] = RB.z;
        LB[(cj + 3) * LBSTR + q] = RB.w;

        // prefetch: B one tile ahead, u/delta two tiles ahead
        if (t + 1 < NT)
            RB = *(const float4*)(Bm + bbase + (ss + T) + cj);
        if (t + 2 < NT) {
            PU[(t + 2) % 3] = *(const float4*)(u + ubase + (ss + 2 * T) + cj);
            PD[(t + 2) % 3] = *(const float4*)(delta + ubase + (ss + 2 * T) + cj);
        }

        const float dc[4] = {softplus_f(PD[cb].x + sbias), softplus_f(PD[cb].y + sbias),
                             softplus_f(PD[cb].z + sbias), softplus_f(PD[cb].w + sbias)};
        const float du[4] = {dc[0] * PU[cb].x, dc[1] * PU[cb].y,
                             dc[2] * PU[cb].z, dc[3] * PU[cb].w};
        sumdt += (dc[0] + dc[1]) + (dc[2] + dc[3]);

#define ASTEP(ii) { \
        const float dt  = dpp_qp<(((ii) >> 2) * 0x55)>(dc[(ii) & 3]); \
        const float dtu = dpp_qp<(((ii) >> 2) * 0x55)>(du[(ii) & 3]); \
        const float4 bv = *(const float4*)(&LB[(ii) * LBSTR + cj]); \
        S[0] = fmaf(exp2_hw(dt * A2[0]), S[0], dtu * bv.x); \
        S[1] = fmaf(exp2_hw(dt * A2[1]), S[1], dtu * bv.y); \
        S[2] = fmaf(exp2_hw(dt * A2[2]), S[2], dtu * bv.z); \
        S[3] = fmaf(exp2_hw(dt * A2[3]), S[3], dtu * bv.w); \
    }
        ASTEP(0)  ASTEP(1)  ASTEP(2)  ASTEP(3)
        ASTEP(4)  ASTEP(5)  ASTEP(6)  ASTEP(7)
        ASTEP(8)  ASTEP(9)  ASTEP(10) ASTEP(11)
        ASTEP(12) ASTEP(13) ASTEP(14) ASTEP(15)
#undef ASTEP
    }

    *(float4*)(S_out + ((size_t)k * NCHAN + ch) * NST + cj) =
        make_float4(S[0], S[1], S[2], S[3]);

    const float sfull = quad_sum(sumdt);
    if (sub == 0) sumdt_out[(size_t)k * NCHAN + ch] = sfull;
}

// ---------------- Phase B: scan chunk summaries -> chunk entry states ----
template<int NCH>
__global__ __launch_bounds__(256) void ssm_phaseB(
    const float* __restrict__ A, const float* __restrict__ sumdt,
    float* __restrict__ S)
{
    const int t  = blockIdx.x * 256 + threadIdx.x;
    const int n  = t & 15;
    const int ch = t >> 4;
    if (ch >= NCHAN) return;
    const int d = ch % DIM;
    const float An2 = A[(size_t)d * NST + n] * LOG2E;

    const size_t kstride = (size_t)NCHAN * NST;
    size_t idx = (size_t)ch * NST + n;

    float x = 0.f;
    float s_nxt = S[idx];
    float p_nxt = sumdt[ch];
#pragma unroll 4
    for (int k = 0; k < NCH; k++) {
        const float s_old = s_nxt;
        const float pdt   = p_nxt;
        if (k + 1 < NCH) {
            s_nxt = S[idx + kstride];
            p_nxt = sumdt[(size_t)(k + 1) * NCHAN + ch];
        }
        S[idx] = x;                                   // x0 for chunk k
        x = fmaf(exp2_hw(An2 * pdt), x, s_old);       // state after chunk k
        idx += kstride;
    }
}

// ---------------- Phase C: replay chunk from x0, emit y ------------------
template<int CLEN>
__global__ __launch_bounds__(256, 8) void ssm_phaseC(
    const float* __restrict__ u, const float* __restrict__ delta,
    const float* __restrict__ Bm, const float* __restrict__ Cm,
    const float* __restrict__ A, const float* __restrict__ Dv,
    const float* __restrict__ dbias, const float* __restrict__ x0,
    float* __restrict__ y)
{
    constexpr int NT = CLEN / T;
    __shared__ float lB[4 * T * LBSTR];
    __shared__ float lC[4 * T * LBSTR];

    const int tid = threadIdx.x;
    const int w   = tid >> 6;
    const int l   = tid & 63;
    const int q   = l >> 2;
    const int sub = l & 3;
    const int cj  = sub << 2;

    const int ch0 = blockIdx.x * 64;
    const int ch  = ch0 + w * 16 + q;
    const int d   = ch % DIM;
    const int bb  = ch0 / DIM;
    const int k   = blockIdx.y;
    const int s0  = k * CLEN;

    float* LB = &lB[w * T * LBSTR];
    float* LC = &lC[w * T * LBSTR];

    float A2[4];
    {
        const float4 av = *(const float4*)(A + (size_t)d * NST + cj);
        A2[0] = av.x * LOG2E; A2[1] = av.y * LOG2E;
        A2[2] = av.z * LOG2E; A2[3] = av.w * LOG2E;
    }
    const float sbias = dbias[d];
    const float Dval  = Dv[d];

    float x[4];
    {
        const float4 xv = *(const float4*)(x0 + ((size_t)k * NCHAN + ch) * NST + cj);
        x[0] = xv.x; x[1] = xv.y; x[2] = xv.z; x[3] = xv.w;
    }

    const size_t ubase = (size_t)ch * SEQ + s0;
    const size_t bbase = ((size_t)bb * NST + q) * SEQ + s0;

    float4 PU[3], PD[3], RB, RC;
    PU[0] = *(const float4*)(u + ubase + cj);
    PD[0] = *(const float4*)(delta + ubase + cj);
    PU[1] = *(const float4*)(u + ubase + T + cj);
    PD[1] = *(const float4*)(delta + ubase + T + cj);
    RB = *(const float4*)(Bm + bbase + cj);
    RC = *(const float4*)(Cm + bbase + cj);

#pragma unroll
    for (int t = 0; t < NT; ++t) {
        const int cb = t % 3;
        const int ss = t * T;

        LB[(cj + 0) * LBSTR + q] = RB.x;
        LB[(cj + 1) * LBSTR + q] = RB.y;
        LB[(cj + 2) * LBSTR + q] = RB.z;
        LB[(cj + 3) * LBSTR + q] = RB.w;
        LC[(cj + 0) * LBSTR + q] = RC.x;
        LC[(cj + 1) * LBSTR + q] = RC.y;
        LC[(cj + 2) * LBSTR + q] = RC.z;
        LC[(cj + 3) * LBSTR + q] = RC.w;

        if (t + 1 < NT) {
            RB = *(const float4*)(Bm + bbase + (ss + T) + cj);
            RC = *(const float4*)(Cm + bbase + (ss + T) + cj);
        }
        if (t + 2 < NT) {
            PU[(t + 2) % 3] = *(const float4*)(u + ubase + (ss + 2 * T) + cj);
            PD[(t + 2) % 3] = *(const float4*)(delta + ubase + (ss + 2 * T) + cj);
        }

        const float dc[4] = {softplus_f(PD[cb].x + sbias), softplus_f(PD[cb].y + sbias),
                             softplus_f(PD[cb].z + sbias), softplus_f(PD[cb].w + sbias)};
        const float du[4] = {dc[0] * PU[cb].x, dc[1] * PU[cb].y,
                             dc[2] * PU[cb].z, dc[3] * PU[cb].w};

        float yreg[4];   // lane sub keeps y for timesteps cj..cj+3

#define CSTEP(ii) { \
        const float dt  = dpp_qp<(((ii) >> 2) * 0x55)>(dc[(ii) & 3]); \
        const float dtu = dpp_qp<(((ii) >> 2) * 0x55)>(du[(ii) & 3]); \
        const float4 bv = *(const float4*)(&LB[(ii) * LBSTR + cj]); \
        const float4 cv = *(const float4*)(&LC[(ii) * LBSTR + cj]); \
        x[0] = fmaf(exp2_hw(dt * A2[0]), x[0], dtu * bv.x); \
        x[1] = fmaf(exp2_hw(dt * A2[1]), x[1], dtu * bv.y); \
        x[2] = fmaf(exp2_hw(dt * A2[2]), x[2], dtu * bv.z); \
        x[3] = fmaf(exp2_hw(dt * A2[3]), x[3], dtu * bv.w); \
        float acc = x[0] * cv.x; \
        acc = fmaf(x[1], cv.y, acc); \
        acc = fmaf(x[2], cv.z, acc); \
        acc = fmaf(x[3], cv.w, acc); \
        acc = quad_sum(acc); \
        if (sub == ((ii) >> 2)) yreg[(ii) & 3] = acc; \
    }
        CSTEP(0)  CSTEP(1)  CSTEP(2)  CSTEP(3)
        CSTEP(4)  CSTEP(5)  CSTEP(6)  CSTEP(7)
        CSTEP(8)  CSTEP(9)  CSTEP(10) CSTEP(11)
        CSTEP(12) CSTEP(13) CSTEP(14) CSTEP(15)
#undef CSTEP

        // fold D*u (own timesteps) and write 64B contiguous per channel row
        yreg[0] = fmaf(Dval, PU[cb].x, yreg[0]);
        yreg[1] = fmaf(Dval, PU[cb].y, yreg[1]);
        yreg[2] = fmaf(Dval, PU[cb].z, yreg[2]);
        yreg[3] = fmaf(Dval, PU[cb].w, yreg[3]);
        *(float4*)(y + ubase + ss + cj) =
            make_float4(yreg[0], yreg[1], yreg[2], yreg[3]);
    }
}

template<int CLEN>
static void run_pipeline(const float* u, const float* delta, const float* Bm,
                         const float* Cm, const float* A, const float* Dv,
                         const float* dbias, float* y, float* ws,
                         hipStream_t stream)
{
    constexpr int NCH = SEQ / CLEN;
    float* sumdt = ws;
    float* S     = ws + (size_t)NCH * NCHAN;

    const dim3 grid(NCHAN / 64, NCH);
    ssm_phaseA<CLEN><<<grid, 256, 0, stream>>>(u, delta, Bm, A, dbias, sumdt, S);
    ssm_phaseB<NCH><<<(NCHAN * NST) / 256, 256, 0, stream>>>(A, sumdt, S);
    ssm_phaseC<CLEN><<<grid, 256, 0, stream>>>(u, delta, Bm, Cm, A, Dv, dbias, S, y);
}

extern "C" void kernel_launch(void* const* d_in, const int* in_sizes, int n_in,
                              void* d_out, int out_size, void* d_ws, size_t ws_size,
                              hipStream_t stream)
{
    const float* u     = (const float*)d_in[0];
    const float* delta = (const float*)d_in[1];
    const float* Bm    = (const float*)d_in[2];
    const float* Cm    = (const float*)d_in[3];
    const float* A     = (const float*)d_in[4];
    const float* Dv    = (const float*)d_in[5];
    const float* dbias = (const float*)d_in[6];
    float* y  = (float*)d_out;
    float* ws = (float*)d_ws;

    // primary: 64 chunks of 64 -> ws = sumdt + S ~ 26.7 MB
    const size_t need64 = ((size_t)64 * NCHAN + (size_t)64 * NCHAN * NST) * sizeof(float);
    if (ws_size >= need64) {
        run_pipeline<64>(u, delta, Bm, Cm, A, Dv, dbias, y, ws, stream);
    } else {
        run_pipeline<128>(u, delta, Bm, Cm, A, Dv, dbias, y, ws, stream);
    }
}